// Round 1
// baseline (129.834 us; speedup 1.0000x reference)
//
#include <hip/hip_runtime.h>
#include <math.h>

// Problem constants
#define SIDE 32
#define NPOS 1024      // SIDE*SIDE
#define NCH 64         // channels
#define KSZ 32         // key size
#define NB 16          // batch
#define R2 36          // radius^2 (6.0^2), mask keeps d <= 6

// Workspace layout (floats):
//  Q   : (B, K, N)   524288
//  Kk  : (B, K, N)   524288
//  VT  : (B, N, K)   524288
//  QXY : (B, 2, N)   32768
//  KXY : (B, 2, N)   32768
#define WS_Q   0
#define WS_K   524288
#define WS_VT  1048576
#define WS_QXY 1572864
#define WS_KXY 1605632

__global__ __launch_bounds__(256) void proj_kernel(
    const float* __restrict__ x,
    const float* __restrict__ Wq, const float* __restrict__ Wk,
    const float* __restrict__ Wv, const float* __restrict__ Wqxy,
    const float* __restrict__ Wkxy,
    float* __restrict__ ws)
{
    __shared__ float w_lds[100 * 64];
    for (int i = threadIdx.x; i < 100 * 64; i += 256) {
        float val;
        if (i < 32 * 64)       val = Wq[i];
        else if (i < 64 * 64)  val = Wk[i - 32 * 64];
        else if (i < 96 * 64)  val = Wv[i - 64 * 64];
        else if (i < 98 * 64)  val = Wqxy[i - 96 * 64];
        else                   val = Wkxy[i - 98 * 64];
        w_lds[i] = val;
    }
    __syncthreads();

    int gid = blockIdx.x * 256 + threadIdx.x;   // b*1024 + n
    int b = gid >> 10, n = gid & 1023;

    float xr[64];
    #pragma unroll
    for (int c = 0; c < 64; c++)
        xr[c] = x[((b * 64 + c) << 10) + n];

    float* Q   = ws + WS_Q;
    float* Kk  = ws + WS_K;
    float* VT  = ws + WS_VT;
    float* QXY = ws + WS_QXY;
    float* KXY = ws + WS_KXY;

    for (int j = 0; j < 100; j++) {
        float acc = 0.f;
        #pragma unroll
        for (int c = 0; c < 64; c++)
            acc += w_lds[j * 64 + c] * xr[c];

        if (j < 32)        Q  [(b << 15) + (j << 10) + n]        = acc;
        else if (j < 64)   Kk [(b << 15) + ((j - 32) << 10) + n] = acc;
        else if (j < 96)   VT [(b << 15) + (n << 5) + (j - 64)]  = acc;
        else if (j < 98)   QXY[(b << 11) + ((j - 96) << 10) + n] = acc;
        else               KXY[(b << 11) + ((j - 98) << 10) + n] = acc;
    }
}

// One wave (64 threads) per query position.
__global__ __launch_bounds__(64) void attn_kernel(
    const float* __restrict__ ws,
    const float* __restrict__ Wout,
    float* __restrict__ out)
{
    const float* Q   = ws + WS_Q;
    const float* Kk  = ws + WS_K;
    const float* VT  = ws + WS_VT;
    const float* QXY = ws + WS_QXY;
    const float* KXY = ws + WS_KXY;

    int qid = blockIdx.x;          // b*1024 + n
    int b = qid >> 10, n = qid & 1023;
    int h = n >> 5, w = n & 31;
    int lane = threadIdx.x;

    __shared__ float p_lds[192];
    __shared__ int   n2_lds[192];
    __shared__ float o_lds[32];

    // Broadcast-load the query vector (same addresses for all lanes -> L1 broadcast)
    float qreg[32];
    #pragma unroll
    for (int k = 0; k < 32; k++)
        qreg[k] = Q[(b << 15) + (k << 10) + n];
    float qxy0 = QXY[(b << 11) + n];
    float qxy1 = QXY[(b << 11) + 1024 + n];

    // Phase 1: scores over the 13x13 candidate neighborhood (3 candidates/lane)
    float s[3];
    int n2s[3];
    #pragma unroll
    for (int t3 = 0; t3 < 3; t3++) {
        int t = lane + t3 * 64;
        float sc = -INFINITY;
        int n2 = -1;
        if (t < 169) {
            int dy = t / 13 - 6, dx = t % 13 - 6;
            int h2 = h + dy, w2 = w + dx;
            if (dy * dy + dx * dx <= R2 && h2 >= 0 && h2 < 32 && w2 >= 0 && w2 < 32) {
                n2 = (h2 << 5) + w2;
                sc = KXY[(b << 11) + n2] * qxy0 + KXY[(b << 11) + 1024 + n2] * qxy1;
                #pragma unroll
                for (int k = 0; k < 32; k++)
                    sc += Kk[(b << 15) + (k << 10) + n2] * qreg[k];
            }
        }
        s[t3] = sc;
        n2s[t3] = n2;
    }

    // Wave-wide softmax (max + sum via shuffles)
    float m = fmaxf(fmaxf(s[0], s[1]), s[2]);
    #pragma unroll
    for (int off = 32; off >= 1; off >>= 1)
        m = fmaxf(m, __shfl_xor(m, off, 64));

    float sum = 0.f;
    #pragma unroll
    for (int t3 = 0; t3 < 3; t3++) {
        float e = (n2s[t3] >= 0) ? __expf(s[t3] - m) : 0.f;
        s[t3] = e;
        sum += e;
    }
    #pragma unroll
    for (int off = 32; off >= 1; off >>= 1)
        sum += __shfl_xor(sum, off, 64);

    #pragma unroll
    for (int t3 = 0; t3 < 3; t3++) {
        p_lds[lane + t3 * 64]  = s[t3];
        n2_lds[lane + t3 * 64] = n2s[t3];
    }
    __syncthreads();

    // Phase 2: PV. lane = (half, k); each half sums 96 candidates, fold with shfl.
    int k = lane & 31, half = lane >> 5;
    float o = 0.f;
    for (int t = half * 96; t < half * 96 + 96; t++) {
        int n2 = n2_lds[t];
        if (n2 >= 0)
            o += p_lds[t] * VT[(b << 15) + (n2 << 5) + k];
    }
    o += __shfl_xor(o, 32, 64);
    if (lane < 32)
        o_lds[lane] = o / sum;
    __syncthreads();

    // Epilogue: y[c] = sum_k Wout[c,k] * o[k], lane = c
    float y = 0.f;
    #pragma unroll
    for (int kk = 0; kk < 32; kk++)
        y += Wout[lane * 32 + kk] * o_lds[kk];
    out[(b << 16) + (lane << 10) + n] = y;
}

extern "C" void kernel_launch(void* const* d_in, const int* in_sizes, int n_in,
                              void* d_out, int out_size, void* d_ws, size_t ws_size,
                              hipStream_t stream) {
    const float* x    = (const float*)d_in[0];
    const float* Wq   = (const float*)d_in[1];
    const float* Wk   = (const float*)d_in[2];
    const float* Wv   = (const float*)d_in[3];
    const float* Wqxy = (const float*)d_in[4];
    const float* Wkxy = (const float*)d_in[5];
    const float* Wout = (const float*)d_in[6];
    float* out = (float*)d_out;
    float* ws  = (float*)d_ws;

    // Kernel 1: projections (q,k,v,q_xy,k_xy), 16384 threads total
    proj_kernel<<<NB * NPOS / 256, 256, 0, stream>>>(x, Wq, Wk, Wv, Wqxy, Wkxy, ws);

    // Kernel 2: fused masked attention + output projection, one wave per query
    attn_kernel<<<NB * NPOS, 64, 0, stream>>>(ws, Wout, out);
}

// Round 2
// 62.227 us; speedup vs baseline: 2.0865x; 2.0865x over previous
//
#include <hip/hip_runtime.h>
#include <math.h>

// Problem: B=16, C=64, H=W=32 (N=1024), K=32, radius 6 (d<=6 kept)

// Workspace float offsets
//  QT  (B,N,32), KT (B,N,32), VT (B,N,32), QXY (B,N,2), KXY (B,N,2)
#define WS_QT   0
#define WS_KT   524288
#define WS_VT   1048576
#define WS_QXY  1572864
#define WS_KXY  1605632

// ---------------- projections: 256 blocks x 256 threads ----------------
// thread = (position within 64-chunk, j-quartile). Wave-uniform j group.
__global__ __launch_bounds__(256) void proj_kernel(
    const float* __restrict__ x,
    const float* __restrict__ Wq, const float* __restrict__ Wk,
    const float* __restrict__ Wv, const float* __restrict__ Wqxy,
    const float* __restrict__ Wkxy,
    float* __restrict__ ws)
{
    __shared__ float w_lds[100 * 64];
    for (int i = threadIdx.x; i < 100 * 64; i += 256) {
        float val;
        if (i < 2048)       val = Wq[i];
        else if (i < 4096)  val = Wk[i - 2048];
        else if (i < 6144)  val = Wv[i - 4096];
        else if (i < 6272)  val = Wqxy[i - 6144];
        else                val = Wkxy[i - 6272];
        w_lds[i] = val;
    }
    __syncthreads();

    int jg = threadIdx.x >> 6;        // 0..3 (wave index -> j group)
    int pl = threadIdx.x & 63;
    int pos = blockIdx.x * 64 + pl;   // 0..16383
    int b = pos >> 10, n = pos & 1023;

    float xr[64];
    #pragma unroll
    for (int c = 0; c < 64; c++)
        xr[c] = x[((b << 6) + c) * 1024 + n];

    float* QT  = ws + WS_QT  + (b << 15);
    float* KT  = ws + WS_KT  + (b << 15);
    float* VT  = ws + WS_VT  + (b << 15);
    float* QXY = ws + WS_QXY + (b << 11);
    float* KXY = ws + WS_KXY + (b << 11);

    int j0 = jg * 25;
    #pragma unroll
    for (int jj = 0; jj < 25; jj++) {
        int j = j0 + jj;
        const float4* wrow = (const float4*)&w_lds[j * 64];
        float acc = 0.f;
        #pragma unroll
        for (int c4 = 0; c4 < 16; c4++) {
            float4 w4 = wrow[c4];
            acc += w4.x * xr[c4*4]   + w4.y * xr[c4*4+1]
                 + w4.z * xr[c4*4+2] + w4.w * xr[c4*4+3];
        }
        if (j < 32)       QT [(n << 5) + j]        = acc;
        else if (j < 64)  KT [(n << 5) + (j - 32)] = acc;
        else if (j < 96)  VT [(n << 5) + (j - 64)] = acc;
        else if (j < 98)  QXY[(n << 1) + (j - 96)] = acc;
        else              KXY[(n << 1) + (j - 98)] = acc;
    }
}

// ---------------- attention: 256 blocks (b x 8x8 tile) x 256 threads ----
// Key region = 20x20 around tile. K then V share one swizzled LDS buffer.
// lane = (query q 0..15 within wave, candidate group cg 0..3).
__global__ __launch_bounds__(256) void attn_kernel(
    const float* __restrict__ ws,
    const float* __restrict__ Wout,
    float* __restrict__ out)
{
    __shared__ float kv_lds[400 * 32];   // 51.2 KB (K phase A, V phase C)
    __shared__ float kxy_lds[2][400];    // 3.2 KB
    __shared__ float w_lds[64 * 32];     // 8 KB

    int tid = threadIdx.x;
    int bid = blockIdx.x;
    int b = bid >> 4, tile = bid & 15;
    int qy0 = (tile >> 2) << 3, qx0 = (tile & 3) << 3;
    int ky0 = qy0 - 6, kx0 = qx0 - 6;

    const float* QT  = ws + WS_QT  + (b << 15);
    const float* KT  = ws + WS_KT  + (b << 15);
    const float* VT  = ws + WS_VT  + (b << 15);
    const float* QXY = ws + WS_QXY + (b << 11);
    const float* KXY = ws + WS_KXY + (b << 11);

    // stage Wout (64x32) with per-row-group xor swizzle (rows 16 apart ->
    // distinct float4 slots so the 4 cg broadcasts hit distinct banks)
    for (int i = tid; i < 512; i += 256) {
        int cch = i >> 3, k4 = i & 7;
        ((float4*)w_lds)[(cch << 3) + (k4 ^ ((cch >> 4) << 1))] =
            ((const float4*)Wout)[i];
    }
    // stage K region (zero-fill out-of-grid)
    for (int i = tid; i < 3200; i += 256) {
        int sl = i >> 3, c4 = i & 7;
        int ry = sl / 20, rx = sl - ry * 20;
        int ky = ky0 + ry, kx = kx0 + rx;
        float4 v = make_float4(0.f, 0.f, 0.f, 0.f);
        if (ky >= 0 && ky < 32 && kx >= 0 && kx < 32)
            v = *(const float4*)&KT[(((ky << 5) + kx) << 5) + (c4 << 2)];
        ((float4*)kv_lds)[(sl << 3) + (c4 ^ (sl & 7))] = v;
    }
    // stage KXY as two planes
    for (int i = tid; i < 400; i += 256) {
        int ry = i / 20, rx = i - ry * 20;
        int ky = ky0 + ry, kx = kx0 + rx;
        float2 v = make_float2(0.f, 0.f);
        if (ky >= 0 && ky < 32 && kx >= 0 && kx < 32)
            v = *(const float2*)&KXY[((ky << 5) + kx) << 1];
        kxy_lds[0][i] = v.x;
        kxy_lds[1][i] = v.y;
    }
    __syncthreads();

    int w = tid >> 6;            // wave -> query rows 2w, 2w+1
    int lane = tid & 63;
    int ql = lane >> 2;          // 0..15
    int cg = lane & 3;           // candidate group
    int r = 2 * w + (ql >> 3);   // tile-local query row
    int c = ql & 7;
    int nq = ((qy0 + r) << 5) + qx0 + c;

    float qreg[32];
    #pragma unroll
    for (int k4 = 0; k4 < 8; k4++) {
        float4 v = *(const float4*)&QT[(nq << 5) + (k4 << 2)];
        qreg[k4*4+0] = v.x; qreg[k4*4+1] = v.y;
        qreg[k4*4+2] = v.z; qreg[k4*4+3] = v.w;
    }
    float qxy0 = QXY[(nq << 1)];
    float qxy1 = QXY[(nq << 1) + 1];

    // Phase A: scores over the wave's 14x20 key-union, cg-strided columns.
    float s[70];
    float m = -INFINITY;
    #pragma unroll
    for (int ur = 0; ur < 14; ur++) {
        int rrow = 2 * w + ur;           // region row 0..19
        int ky = ky0 + rrow;
        int dy = ur - 6 - (ql >> 3);
        #pragma unroll
        for (int u4 = 0; u4 < 5; u4++) {
            int ucol = u4 * 4 + cg;
            int sl = rrow * 20 + ucol;
            int kx = kx0 + ucol;
            int dx = ucol - 6 - c;
            const float4* krow = (const float4*)&kv_lds[sl << 5];
            int sw = sl & 7;
            float acc = kxy_lds[0][sl] * qxy0 + kxy_lds[1][sl] * qxy1;
            #pragma unroll
            for (int k4 = 0; k4 < 8; k4++) {
                float4 kv = krow[k4 ^ sw];
                acc += kv.x * qreg[k4*4]   + kv.y * qreg[k4*4+1]
                     + kv.z * qreg[k4*4+2] + kv.w * qreg[k4*4+3];
            }
            bool valid = (dy*dy + dx*dx <= 36) && (ky >= 0) && (ky < 32)
                      && (kx >= 0) && (kx < 32);
            float sc = valid ? acc : -INFINITY;
            s[ur*5+u4] = sc;
            m = fmaxf(m, sc);
        }
    }
    // softmax across the 4-lane quad of each query
    m = fmaxf(m, __shfl_xor(m, 1, 64));
    m = fmaxf(m, __shfl_xor(m, 2, 64));
    float sum = 0.f;
    #pragma unroll
    for (int kk = 0; kk < 70; kk++) {
        float e = __expf(s[kk] - m);   // -inf -> 0
        s[kk] = e;
        sum += e;
    }
    sum += __shfl_xor(sum, 1, 64);
    sum += __shfl_xor(sum, 2, 64);
    float rinv = 1.f / sum;

    __syncthreads();
    // stage V region over K buffer
    for (int i = tid; i < 3200; i += 256) {
        int sl = i >> 3, c4 = i & 7;
        int ry = sl / 20, rx = sl - ry * 20;
        int ky = ky0 + ry, kx = kx0 + rx;
        float4 v = make_float4(0.f, 0.f, 0.f, 0.f);
        if (ky >= 0 && ky < 32 && kx >= 0 && kx < 32)
            v = *(const float4*)&VT[(((ky << 5) + kx) << 5) + (c4 << 2)];
        ((float4*)kv_lds)[(sl << 3) + (c4 ^ (sl & 7))] = v;
    }
    __syncthreads();

    // Phase C: PV (p==0 terms vanish; zero-filled OOB rows harmless)
    float o[32];
    #pragma unroll
    for (int k = 0; k < 32; k++) o[k] = 0.f;
    #pragma unroll
    for (int ur = 0; ur < 14; ur++) {
        int rrow = 2 * w + ur;
        #pragma unroll
        for (int u4 = 0; u4 < 5; u4++) {
            int sl = rrow * 20 + u4 * 4 + cg;
            float pv = s[ur*5+u4];
            const float4* vrow = (const float4*)&kv_lds[sl << 5];
            int sw = sl & 7;
            #pragma unroll
            for (int k4 = 0; k4 < 8; k4++) {
                float4 vv = vrow[k4 ^ sw];
                o[k4*4]   += pv * vv.x; o[k4*4+1] += pv * vv.y;
                o[k4*4+2] += pv * vv.z; o[k4*4+3] += pv * vv.w;
            }
        }
    }
    #pragma unroll
    for (int k = 0; k < 32; k++) {
        o[k] += __shfl_xor(o[k], 1, 64);
        o[k] += __shfl_xor(o[k], 2, 64);
        o[k] *= rinv;
    }

    // Epilogue: each lane does 16 output channels from registers
    float* outb = out + (b << 16);
    #pragma unroll
    for (int cc = 0; cc < 16; cc++) {
        int ch = (cg << 4) + cc;
        const float4* wrow = (const float4*)&w_lds[ch << 5];
        int sw2 = (cg << 1);
        float y = 0.f;
        #pragma unroll
        for (int k4 = 0; k4 < 8; k4++) {
            float4 wv = wrow[k4 ^ sw2];
            y += wv.x * o[k4*4]   + wv.y * o[k4*4+1]
               + wv.z * o[k4*4+2] + wv.w * o[k4*4+3];
        }
        outb[(ch << 10) + nq] = y;
    }
}

extern "C" void kernel_launch(void* const* d_in, const int* in_sizes, int n_in,
                              void* d_out, int out_size, void* d_ws, size_t ws_size,
                              hipStream_t stream) {
    const float* x    = (const float*)d_in[0];
    const float* Wq   = (const float*)d_in[1];
    const float* Wk   = (const float*)d_in[2];
    const float* Wv   = (const float*)d_in[3];
    const float* Wqxy = (const float*)d_in[4];
    const float* Wkxy = (const float*)d_in[5];
    const float* Wout = (const float*)d_in[6];
    float* out = (float*)d_out;
    float* ws  = (float*)d_ws;

    proj_kernel<<<256, 256, 0, stream>>>(x, Wq, Wk, Wv, Wqxy, Wkxy, ws);
    attn_kernel<<<256, 256, 0, stream>>>(ws, Wout, out);
}

// Round 4
// 51.339 us; speedup vs baseline: 2.5290x; 1.2121x over previous
//
#include <hip/hip_runtime.h>
#include <math.h>

typedef short bf16x8 __attribute__((ext_vector_type(8)));
typedef float f32x4 __attribute__((ext_vector_type(4)));
typedef unsigned short u16;
typedef unsigned int u32;

// ws byte offsets: QT (B,N,32) bf16, KT (B,N,32) bf16,
// VW (B,32,1032) bf16 (1024 + 8 pad per kd row, pad zeroed by proj),
// QXY (B,N,2) f32, KXY (B,N,2) f32
#define WS_QT  0
#define WS_KT  1048576
#define WS_VW  2097152
#define WS_QXY 3153920
#define WS_KXY 3284992
#define VWS    1032

__device__ __forceinline__ u16 f2bf(float f) {
    u32 u = __float_as_uint(f);
    u += 0x7fffu + ((u >> 16) & 1u);
    return (u16)(u >> 16);
}

// ---------- projections: thread = (pos, j-quarter), weights wave-uniform ----------
__global__ __launch_bounds__(256) void proj_kernel(
    const float* __restrict__ x,
    const float* __restrict__ Wq, const float* __restrict__ Wk,
    const float* __restrict__ Wv, const float* __restrict__ Wqxy,
    const float* __restrict__ Wkxy, char* __restrict__ wsb)
{
    u16* QT = (u16*)(wsb + WS_QT);
    u16* KT = (u16*)(wsb + WS_KT);
    u16* VW = (u16*)(wsb + WS_VW);
    float* QXY = (float*)(wsb + WS_QXY);
    float* KXY = (float*)(wsb + WS_KXY);

    int jg = threadIdx.x >> 6;                       // wave-uniform j group
    int pos = (blockIdx.x << 6) + (threadIdx.x & 63);
    int b = pos >> 10, n = pos & 1023;

    // zero the VW row pads (8 u16 per kd row) so OOB-region staging reads
    // are finite (masked later, but must not be NaN: 0 * NaN = NaN in MFMA)
    if (jg == 0 && n < 8) {
        #pragma unroll
        for (int kd = 0; kd < 32; kd++)
            VW[((b << 5) + kd) * VWS + 1024 + n] = 0;
    }

    float xr[64];
    #pragma unroll
    for (int c = 0; c < 64; c++) xr[c] = x[(((b << 6) + c) << 10) + n];

    int nb32 = ((b << 10) + n) << 5;
    #pragma unroll
    for (int jj = 0; jj < 25; jj++) {
        int j = jg * 25 + jj;
        const float* wrow;
        if (j < 32)      wrow = Wq   + (j << 6);
        else if (j < 64) wrow = Wk   + ((j - 32) << 6);
        else if (j < 96) wrow = Wv   + ((j - 64) << 6);
        else if (j < 98) wrow = Wqxy + ((j - 96) << 6);
        else             wrow = Wkxy + ((j - 98) << 6);
        float acc = 0.f;
        #pragma unroll
        for (int c = 0; c < 64; c++) acc += wrow[c] * xr[c];
        if (j < 32)      QT[nb32 + j] = f2bf(acc);
        else if (j < 64) KT[nb32 + (j - 32)] = f2bf(acc);
        else if (j < 96) VW[((b << 5) + (j - 64)) * VWS + n] = f2bf(acc);
        else if (j < 98) QXY[(((b << 10) + n) << 1) + (j - 96)] = acc;
        else             KXY[(((b << 10) + n) << 1) + (j - 98)] = acc;
    }
}

// ---------- attention: 512 blocks = (b, 4x8-query tile); 4 waves = (m, kh) ----------
// Region: 20 rows x 16 cols = 320 slots; slot = sr*16+sc.
// MFMA 16x16x32 bf16. A/B staged with identical per-lane k maps (any k-perm
// cancels); C/D (HW-verified): col=lane&15, row=(lane>>4)*4+reg.
__global__ __launch_bounds__(256) void attn_kernel(
    const char* __restrict__ wsb, const float* __restrict__ Wout,
    float* __restrict__ out)
{
    const u16* QT = (const u16*)(wsb + WS_QT);
    const u16* KT = (const u16*)(wsb + WS_KT);
    const u16* VW = (const u16*)(wsb + WS_VW);
    const float* QXY = (const float*)(wsb + WS_QXY);
    const float* KXY = (const float*)(wsb + WS_KXY);

    __shared__ __align__(16) u16 kfr[20 * 64 * 8];   // K B-frags per region row
    __shared__ __align__(16) u16 vfr[20 * 64 * 8];   // V B-frags per (kk,nt)
    __shared__ __align__(16) u16 qfr[2 * 64 * 8];    // Q A-frags per m-tile
    __shared__ __align__(16) u16 wfr[4 * 64 * 8];    // Wout^T B-frags per nt
    __shared__ __align__(16) u16 Pl[32 * 328];       // P rows (stride 328)
    __shared__ __align__(16) float kxy2[320 * 2];
    __shared__ __align__(16) float qxy2[32 * 2];
    __shared__ __align__(16) float olds[32 * 36];    // O exchange (stride 36)
    __shared__ __align__(16) float mbuf[64];
    __shared__ __align__(16) float sbuf[64];

    int tid = threadIdx.x;
    int bid = blockIdx.x;
    int b = bid >> 5, t5 = bid & 31;
    int qy0 = (t5 >> 3) << 3;
    int qx0 = (t5 & 7) << 2;
    int ry0 = qy0 - 6, rx0 = qx0 - 6;

    // stage K fragments (1280 16B chunks); OOB clamped (masked later)
    #pragma unroll
    for (int i = 0; i < 5; i++) {
        int c = tid + i * 256;
        int slot = c >> 2, ch4 = c & 3;
        int sr = slot >> 4, sc = slot & 15;
        int n2 = (ry0 + sr) * 32 + rx0 + sc;
        n2 = max(0, min(1023, n2));
        uint4 d = *(const uint4*)(KT + ((((b << 10) + n2) << 5) + (ch4 << 3)));
        *(uint4*)&kfr[((sr << 6) + (ch4 << 4) + sc) << 3] = d;
    }
    // stage V fragments (1280 16B chunks). VW rows padded to 1032 so the
    // 8-slot span never crosses a kd row; OOB slots read pad/garbage but are
    // masked (p=0) and finite. No clamp (negative offsets stay inside ws).
    #pragma unroll
    for (int i = 0; i < 5; i++) {
        int c = tid + i * 256;
        int kk = c >> 7, r = c & 127;
        int nt = r >> 6, kg4 = (r >> 4) & 3, cl2 = r & 15;
        int kd = (nt << 4) + cl2;
        int slotb = (kk << 5) + (kg4 << 3);
        int n2b = (ry0 + (slotb >> 4)) * 32 + rx0 + (slotb & 15);
        const u32* src = (const u32*)(VW + ((b << 5) + kd) * VWS + n2b);
        uint4 d; d.x = src[0]; d.y = src[1]; d.z = src[2]; d.w = src[3];
        *(uint4*)&vfr[((((kk << 1) + nt) << 6) + (kg4 << 4) + cl2) << 3] = d;
    }
    // stage Q fragments
    if (tid < 128) {
        int mm = tid >> 6, l = tid & 63;
        int q = (mm << 4) + (l & 15);
        int nq = (qy0 + (q >> 2)) * 32 + qx0 + (q & 3);
        uint4 d = *(const uint4*)(QT + ((((b << 10) + nq) << 5) + ((l >> 4) << 3)));
        *(uint4*)&qfr[tid << 3] = d;
    }
    // stage Wout^T fragments (fp32 -> bf16)
    {
        int nt = tid >> 6, l = tid & 63;
        int cc = (nt << 4) + (l & 15);
        const float* wsrc = Wout + (cc << 5) + ((l >> 4) << 3);
        u32 p0 = (u32)f2bf(wsrc[0]) | ((u32)f2bf(wsrc[1]) << 16);
        u32 p1 = (u32)f2bf(wsrc[2]) | ((u32)f2bf(wsrc[3]) << 16);
        u32 p2 = (u32)f2bf(wsrc[4]) | ((u32)f2bf(wsrc[5]) << 16);
        u32 p3 = (u32)f2bf(wsrc[6]) | ((u32)f2bf(wsrc[7]) << 16);
        uint4 d; d.x = p0; d.y = p1; d.z = p2; d.w = p3;
        *(uint4*)&wfr[tid << 3] = d;
    }
    // stage kxy / qxy
    for (int i = tid; i < 320; i += 256) {
        int n2 = (ry0 + (i >> 4)) * 32 + rx0 + (i & 15);
        n2 = max(0, min(1023, n2));
        float2 v = *(const float2*)(KXY + (((b << 10) + n2) << 1));
        *(float2*)&kxy2[i << 1] = v;
    }
    if (tid < 32) {
        int nq = (qy0 + (tid >> 2)) * 32 + qx0 + (tid & 3);
        float2 v = *(const float2*)(QXY + (((b << 10) + nq) << 1));
        *(float2*)&qxy2[tid << 1] = v;
    }
    for (int i = tid; i < 32 * 36; i += 256) olds[i] = 0.f;

    __syncthreads();

    int wid = tid >> 6, ll = tid & 63;
    int m = wid & 1, kh = wid >> 1;
    int cl = ll & 15, kg = ll >> 4;

    // ---- QK^T: 10 MFMAs over this wave's 10 region rows
    bf16x8 aq = *(bf16x8*)&qfr[((m << 6) + ll) << 3];
    f32x4 acc[10];
    #pragma unroll
    for (int t = 0; t < 10; t++) {
        int rr = kh * 10 + t;
        bf16x8 bk = *(bf16x8*)&kfr[((rr << 6) + ll) << 3];
        f32x4 z = {0.f, 0.f, 0.f, 0.f};
        acc[t] = __builtin_amdgcn_mfma_f32_16x16x32_bf16(aq, bk, z, 0, 0, 0);
    }

    // ---- mask + xy scores + row max
    int qrl = (m << 2) + kg;            // query row within 8-row tile
    int dybase = kh * 10 - 6 - qrl;
    int kxv = rx0 + cl;
    bool kxok = (kxv >= 0) && (kxv < 32);
    float qa[4], qb[4]; int dx2c[4];
    #pragma unroll
    for (int r = 0; r < 4; r++) {
        int q = (m << 4) + (kg << 2) + r;
        float2 qv = *(float2*)&qxy2[q << 1];
        qa[r] = qv.x; qb[r] = qv.y;
        int dx = cl - 6 - r;
        dx2c[r] = dx * dx;
    }
    float mh[4] = {-1e30f, -1e30f, -1e30f, -1e30f};
    #pragma unroll
    for (int t = 0; t < 10; t++) {
        int rr = kh * 10 + t;
        int ky = ry0 + rr;
        bool kyok = (ky >= 0) && (ky < 32);
        float2 kv = *(float2*)&kxy2[((rr << 4) + cl) << 1];
        int dy = dybase + t, dy2 = dy * dy;
        #pragma unroll
        for (int r = 0; r < 4; r++) {
            float s = acc[t][r] + qa[r] * kv.x + qb[r] * kv.y;
            bool ok = kyok && kxok && (dy2 + dx2c[r] <= 36);
            acc[t][r] = ok ? s : -1e4f;
            mh[r] = fmaxf(mh[r], acc[t][r]);
        }
    }
    #pragma unroll
    for (int s = 1; s < 16; s <<= 1) {
        #pragma unroll
        for (int r = 0; r < 4; r++) mh[r] = fmaxf(mh[r], __shfl_xor(mh[r], s, 64));
    }
    if (cl == 0) {
        float4 t4 = make_float4(mh[0], mh[1], mh[2], mh[3]);
        *(float4*)&mbuf[(kh << 5) + (m << 4) + (kg << 2)] = t4;
    }
    __syncthreads();
    float4 om = *(float4*)&mbuf[((kh ^ 1) << 5) + (m << 4) + (kg << 2)];
    float mf[4];
    mf[0] = fmaxf(mh[0], om.x); mf[1] = fmaxf(mh[1], om.y);
    mf[2] = fmaxf(mh[2], om.z); mf[3] = fmaxf(mh[3], om.w);

    // ---- exp + row sum (cross-wave via sbuf), write P (bf16)
    float sh[4] = {0.f, 0.f, 0.f, 0.f};
    #pragma unroll
    for (int t = 0; t < 10; t++) {
        #pragma unroll
        for (int r = 0; r < 4; r++) {
            float p = __expf(acc[t][r] - mf[r]);
            acc[t][r] = p;
            sh[r] += p;
        }
    }
    #pragma unroll
    for (int s = 1; s < 16; s <<= 1) {
        #pragma unroll
        for (int r = 0; r < 4; r++) sh[r] += __shfl_xor(sh[r], s, 64);
    }
    if (cl == 0) {
        float4 t4 = make_float4(sh[0], sh[1], sh[2], sh[3]);
        *(float4*)&sbuf[(kh << 5) + (m << 4) + (kg << 2)] = t4;
    }
    #pragma unroll
    for (int t = 0; t < 10; t++) {
        int slot = ((kh * 10 + t) << 4) + cl;
        #pragma unroll
        for (int r = 0; r < 4; r++) {
            int q = (m << 4) + (kg << 2) + r;
            Pl[q * 328 + slot] = f2bf(acc[t][r]);
        }
    }
    __syncthreads();
    float4 os = *(float4*)&sbuf[((kh ^ 1) << 5) + (m << 4) + (kg << 2)];
    float rinv[4];
    rinv[0] = 1.f / (sh[0] + os.x); rinv[1] = 1.f / (sh[1] + os.y);
    rinv[2] = 1.f / (sh[2] + os.z); rinv[3] = 1.f / (sh[3] + os.w);

    // ---- PV: this wave's 5 k-tiles (its own P writes), 2 kd n-tiles
    f32x4 oacc0 = {0.f, 0.f, 0.f, 0.f}, oacc1 = {0.f, 0.f, 0.f, 0.f};
    int arow = (m << 4) + cl;
    #pragma unroll
    for (int i2 = 0; i2 < 5; i2++) {
        int kk = kh * 5 + i2;
        bf16x8 ap = *(bf16x8*)&Pl[arow * 328 + (kk << 5) + (kg << 3)];
        bf16x8 bv0 = *(bf16x8*)&vfr[(((kk << 1) << 6) + ll) << 3];
        bf16x8 bv1 = *(bf16x8*)&vfr[((((kk << 1) + 1) << 6) + ll) << 3];
        oacc0 = __builtin_amdgcn_mfma_f32_16x16x32_bf16(ap, bv0, oacc0, 0, 0, 0);
        oacc1 = __builtin_amdgcn_mfma_f32_16x16x32_bf16(ap, bv1, oacc1, 0, 0, 0);
    }
    // normalized partial-O accumulation across kh halves
    #pragma unroll
    for (int r = 0; r < 4; r++) {
        int q = (m << 4) + (kg << 2) + r;
        atomicAdd(&olds[q * 36 + cl],      oacc0[r] * rinv[r]);
        atomicAdd(&olds[q * 36 + cl + 16], oacc1[r] * rinv[r]);
    }
    __syncthreads();

    // ---- epilogue: Y = O * Wout^T via MFMA, scattered f32 stores
    int qe = (m << 4) + cl;
    float4 o1 = *(float4*)&olds[qe * 36 + (kg << 3)];
    float4 o2 = *(float4*)&olds[qe * 36 + (kg << 3) + 4];
    bf16x8 aO;
    aO[0] = (short)f2bf(o1.x); aO[1] = (short)f2bf(o1.y);
    aO[2] = (short)f2bf(o1.z); aO[3] = (short)f2bf(o1.w);
    aO[4] = (short)f2bf(o2.x); aO[5] = (short)f2bf(o2.y);
    aO[6] = (short)f2bf(o2.z); aO[7] = (short)f2bf(o2.w);

    int nqb = (qy0 + qrl) * 32 + qx0;
    #pragma unroll
    for (int e = 0; e < 2; e++) {
        int nt2 = (kh << 1) + e;
        bf16x8 bw = *(bf16x8*)&wfr[((nt2 << 6) + ll) << 3];
        f32x4 z = {0.f, 0.f, 0.f, 0.f};
        f32x4 y = __builtin_amdgcn_mfma_f32_16x16x32_bf16(aO, bw, z, 0, 0, 0);
        int cc = cl + (nt2 << 4);
        #pragma unroll
        for (int r = 0; r < 4; r++)
            out[(((b << 6) + cc) << 10) + nqb + r] = y[r];
    }
}

extern "C" void kernel_launch(void* const* d_in, const int* in_sizes, int n_in,
                              void* d_out, int out_size, void* d_ws, size_t ws_size,
                              hipStream_t stream) {
    const float* x    = (const float*)d_in[0];
    const float* Wq   = (const float*)d_in[1];
    const float* Wk   = (const float*)d_in[2];
    const float* Wv   = (const float*)d_in[3];
    const float* Wqxy = (const float*)d_in[4];
    const float* Wkxy = (const float*)d_in[5];
    const float* Wout = (const float*)d_in[6];
    float* out = (float*)d_out;
    char* wsb  = (char*)d_ws;

    proj_kernel<<<256, 256, 0, stream>>>(x, Wq, Wk, Wv, Wqxy, Wkxy, wsb);
    attn_kernel<<<512, 256, 0, stream>>>(wsb, Wout, out);
}

// Round 5
// 35.554 us; speedup vs baseline: 3.6517x; 1.4440x over previous
//
#include <hip/hip_runtime.h>
#include <math.h>

typedef short bf16x8 __attribute__((ext_vector_type(8)));
typedef float f32x4 __attribute__((ext_vector_type(4)));
typedef unsigned short u16;
typedef unsigned int u32;

// ws byte offsets: QT (B,N,32) bf16, KT (B,N,32) bf16,
// VW (B,32,1032) bf16 (1024 + 8 pad per kd row, pad zeroed by proj),
// QXY (B,N,2) f32, KXY (B,N,2) f32
#define WS_QT  0
#define WS_KT  1048576
#define WS_VW  2097152
#define WS_QXY 3153920
#define WS_KXY 3284992
#define VWS    1032

__device__ __forceinline__ u16 f2bf(float f) {
    u32 u = __float_as_uint(f);
    u += 0x7fffu + ((u >> 16) & 1u);
    return (u16)(u >> 16);
}
__device__ __forceinline__ u32 pk2(float a, float b) {
    return (u32)f2bf(a) | ((u32)f2bf(b) << 16);
}

// ---------- projections: 256 blocks x 256 threads ----------
// Weights staged in LDS (float4 broadcast reads); outputs staged in o_lds so
// every global store is a coalesced uint4/float2. 4 independent FMA chains.
__global__ __launch_bounds__(256) void proj_kernel(
    const float* __restrict__ x,
    const float* __restrict__ Wq, const float* __restrict__ Wk,
    const float* __restrict__ Wv, const float* __restrict__ Wqxy,
    const float* __restrict__ Wkxy, char* __restrict__ wsb)
{
    u16* QT = (u16*)(wsb + WS_QT);
    u16* KT = (u16*)(wsb + WS_KT);
    u16* VW = (u16*)(wsb + WS_VW);
    float* QXY = (float*)(wsb + WS_QXY);
    float* KXY = (float*)(wsb + WS_KXY);

    __shared__ float w_lds[100 * 64];    // 25.6 KB
    __shared__ float o_lds[64 * 101];    // 25.9 KB, stride 101 (conflict-free)

    int tid = threadIdx.x;
    // stage all weights as float4
    for (int i = tid; i < 1600; i += 256) {
        float4 v;
        if (i < 512)       v = ((const float4*)Wq)[i];
        else if (i < 1024) v = ((const float4*)Wk)[i - 512];
        else if (i < 1536) v = ((const float4*)Wv)[i - 1024];
        else if (i < 1568) v = ((const float4*)Wqxy)[i - 1536];
        else               v = ((const float4*)Wkxy)[i - 1568];
        ((float4*)w_lds)[i] = v;
    }

    int lane = tid & 63, jg = tid >> 6;
    int pos = (blockIdx.x << 6) + lane;          // 64 positions per block
    int b = pos >> 10, n = pos & 1023;
    int n0 = (blockIdx.x << 6) & 1023;           // block-base n (same b for all 64)

    float xr[64];
    #pragma unroll
    for (int c = 0; c < 64; c++) xr[c] = x[(((b << 6) + c) << 10) + n];

    __syncthreads();

    #pragma unroll
    for (int jj = 0; jj < 25; jj++) {
        int j = jg * 25 + jj;
        const float4* wr = (const float4*)&w_lds[j << 6];
        float a0 = 0.f, a1 = 0.f, a2 = 0.f, a3 = 0.f;
        #pragma unroll
        for (int c4 = 0; c4 < 16; c4++) {
            float4 w4 = wr[c4];
            a0 += w4.x * xr[c4 * 4];
            a1 += w4.y * xr[c4 * 4 + 1];
            a2 += w4.z * xr[c4 * 4 + 2];
            a3 += w4.w * xr[c4 * 4 + 3];
        }
        o_lds[lane * 101 + j] = (a0 + a1) + (a2 + a3);
    }
    __syncthreads();

    // Round A: QT rows as contiguous uint4 chunks (fully coalesced)
    {
        int p = tid >> 2, qr = tid & 3;
        const float* src = &o_lds[p * 101 + (qr << 3)];
        uint4 d;
        d.x = pk2(src[0], src[1]); d.y = pk2(src[2], src[3]);
        d.z = pk2(src[4], src[5]); d.w = pk2(src[6], src[7]);
        *(uint4*)&QT[(((b << 10) + n0 + p) << 5) + (qr << 3)] = d;
    }
    // Round B: KT
    {
        int p = tid >> 2, qr = tid & 3;
        const float* src = &o_lds[p * 101 + 32 + (qr << 3)];
        uint4 d;
        d.x = pk2(src[0], src[1]); d.y = pk2(src[2], src[3]);
        d.z = pk2(src[4], src[5]); d.w = pk2(src[6], src[7]);
        *(uint4*)&KT[(((b << 10) + n0 + p) << 5) + (qr << 3)] = d;
    }
    // Round C: VW (transposed): thread=(kd, octet of 8 positions)
    {
        int kd = tid >> 3, oc = tid & 7;
        const float* col = &o_lds[(oc << 3) * 101 + 64 + kd];
        uint4 d;
        d.x = pk2(col[0], col[101]);       d.y = pk2(col[202], col[303]);
        d.z = pk2(col[404], col[505]);     d.w = pk2(col[606], col[707]);
        *(uint4*)&VW[((b << 5) + kd) * VWS + n0 + (oc << 3)] = d;
    }
    // Round D: QXY/KXY + VW row pads (one block per batch writes pads)
    if (tid < 64) {
        int p = tid;
        const float* src = &o_lds[p * 101 + 96];
        *(float2*)&QXY[((b << 10) + n0 + p) << 1] = make_float2(src[0], src[1]);
        *(float2*)&KXY[((b << 10) + n0 + p) << 1] = make_float2(src[2], src[3]);
    } else if (tid >= 128 && tid < 160 && (blockIdx.x & 15) == 15) {
        int kd = tid - 128;
        uint4 z = make_uint4(0, 0, 0, 0);
        *(uint4*)&VW[((b << 5) + kd) * VWS + 1024] = z;   // zero the 8-u16 pad
    }
}

// ---------- attention: 512 blocks = (b, 4x8-query tile); 4 waves = (m, kh) ----------
// Region: 20 rows x 16 cols = 320 slots; slot = sr*16+sc.
// MFMA 16x16x32 bf16. A/B staged with identical per-lane k maps (any k-perm
// cancels); C/D (HW-verified): col=lane&15, row=(lane>>4)*4+reg.
__global__ __launch_bounds__(256) void attn_kernel(
    const char* __restrict__ wsb, const float* __restrict__ Wout,
    float* __restrict__ out)
{
    const u16* QT = (const u16*)(wsb + WS_QT);
    const u16* KT = (const u16*)(wsb + WS_KT);
    const u16* VW = (const u16*)(wsb + WS_VW);
    const float* QXY = (const float*)(wsb + WS_QXY);
    const float* KXY = (const float*)(wsb + WS_KXY);

    __shared__ __align__(16) u16 kfr[20 * 64 * 8];   // K B-frags per region row
    __shared__ __align__(16) u16 vfr[20 * 64 * 8];   // V B-frags per (kk,nt)
    __shared__ __align__(16) u16 qfr[2 * 64 * 8];    // Q A-frags per m-tile
    __shared__ __align__(16) u16 wfr[4 * 64 * 8];    // Wout^T B-frags per nt
    __shared__ __align__(16) u16 Pl[32 * 328];       // P rows (stride 328)
    __shared__ __align__(16) float kxy2[320 * 2];
    __shared__ __align__(16) float qxy2[32 * 2];
    __shared__ __align__(16) float olds[32 * 36];    // O exchange (stride 36)
    __shared__ __align__(16) float mbuf[64];
    __shared__ __align__(16) float sbuf[64];

    int tid = threadIdx.x;
    int bid = blockIdx.x;
    int b = bid >> 5, t5 = bid & 31;
    int qy0 = (t5 >> 3) << 3;
    int qx0 = (t5 & 7) << 2;
    int ry0 = qy0 - 6, rx0 = qx0 - 6;

    // stage K fragments (1280 16B chunks); OOB clamped (masked later)
    #pragma unroll
    for (int i = 0; i < 5; i++) {
        int c = tid + i * 256;
        int slot = c >> 2, ch4 = c & 3;
        int sr = slot >> 4, sc = slot & 15;
        int n2 = (ry0 + sr) * 32 + rx0 + sc;
        n2 = max(0, min(1023, n2));
        uint4 d = *(const uint4*)(KT + ((((b << 10) + n2) << 5) + (ch4 << 3)));
        *(uint4*)&kfr[((sr << 6) + (ch4 << 4) + sc) << 3] = d;
    }
    // stage V fragments (1280 16B chunks). VW rows padded to 1032 so an
    // 8-slot span never crosses a kd row: in-row negative offsets land in the
    // previous row's zeroed pad (valid tail slots still read correct data).
    // Rows fully outside the grid are masked -> redirect to row start so the
    // read stays inside VW (finite bf16; p=0 kills it).
    #pragma unroll
    for (int i = 0; i < 5; i++) {
        int c = tid + i * 256;
        int kk = c >> 7, r = c & 127;
        int nt = r >> 6, kg4 = (r >> 4) & 3, cl2 = r & 15;
        int kd = (nt << 4) + cl2;
        int slotb = (kk << 5) + (kg4 << 3);
        int ky2 = ry0 + (slotb >> 4);
        int n2b = ky2 * 32 + rx0 + (slotb & 15);
        if ((u32)ky2 > 31u) n2b = 0;
        const u32* src = (const u32*)(VW + ((b << 5) + kd) * VWS + n2b);
        uint4 d; d.x = src[0]; d.y = src[1]; d.z = src[2]; d.w = src[3];
        *(uint4*)&vfr[((((kk << 1) + nt) << 6) + (kg4 << 4) + cl2) << 3] = d;
    }
    // stage Q fragments
    if (tid < 128) {
        int mm = tid >> 6, l = tid & 63;
        int q = (mm << 4) + (l & 15);
        int nq = (qy0 + (q >> 2)) * 32 + qx0 + (q & 3);
        uint4 d = *(const uint4*)(QT + ((((b << 10) + nq) << 5) + ((l >> 4) << 3)));
        *(uint4*)&qfr[tid << 3] = d;
    }
    // stage Wout^T fragments (fp32 -> bf16)
    {
        int nt = tid >> 6, l = tid & 63;
        int cc = (nt << 4) + (l & 15);
        const float* wsrc = Wout + (cc << 5) + ((l >> 4) << 3);
        uint4 d;
        d.x = pk2(wsrc[0], wsrc[1]); d.y = pk2(wsrc[2], wsrc[3]);
        d.z = pk2(wsrc[4], wsrc[5]); d.w = pk2(wsrc[6], wsrc[7]);
        *(uint4*)&wfr[tid << 3] = d;
    }
    // stage kxy / qxy
    for (int i = tid; i < 320; i += 256) {
        int n2 = (ry0 + (i >> 4)) * 32 + rx0 + (i & 15);
        n2 = max(0, min(1023, n2));
        float2 v = *(const float2*)(KXY + (((b << 10) + n2) << 1));
        *(float2*)&kxy2[i << 1] = v;
    }
    if (tid < 32) {
        int nq = (qy0 + (tid >> 2)) * 32 + qx0 + (tid & 3);
        float2 v = *(const float2*)(QXY + (((b << 10) + nq) << 1));
        *(float2*)&qxy2[tid << 1] = v;
    }
    for (int i = tid; i < 32 * 36; i += 256) olds[i] = 0.f;

    __syncthreads();

    int wid = tid >> 6, ll = tid & 63;
    int m = wid & 1, kh = wid >> 1;
    int cl = ll & 15, kg = ll >> 4;

    // ---- QK^T: 10 MFMAs over this wave's 10 region rows
    bf16x8 aq = *(bf16x8*)&qfr[((m << 6) + ll) << 3];
    f32x4 acc[10];
    #pragma unroll
    for (int t = 0; t < 10; t++) {
        int rr = kh * 10 + t;
        bf16x8 bk = *(bf16x8*)&kfr[((rr << 6) + ll) << 3];
        f32x4 z = {0.f, 0.f, 0.f, 0.f};
        acc[t] = __builtin_amdgcn_mfma_f32_16x16x32_bf16(aq, bk, z, 0, 0, 0);
    }

    // ---- mask + xy scores + row max
    int qrl = (m << 2) + kg;            // query row within 8-row tile
    int dybase = kh * 10 - 6 - qrl;
    int kxv = rx0 + cl;
    bool kxok = (kxv >= 0) && (kxv < 32);
    float qa[4], qb[4]; int dx2c[4];
    #pragma unroll
    for (int r = 0; r < 4; r++) {
        int q = (m << 4) + (kg << 2) + r;
        float2 qv = *(float2*)&qxy2[q << 1];
        qa[r] = qv.x; qb[r] = qv.y;
        int dx = cl - 6 - r;
        dx2c[r] = dx * dx;
    }
    float mh[4] = {-1e30f, -1e30f, -1e30f, -1e30f};
    #pragma unroll
    for (int t = 0; t < 10; t++) {
        int rr = kh * 10 + t;
        int ky = ry0 + rr;
        bool kyok = (ky >= 0) && (ky < 32);
        float2 kv = *(float2*)&kxy2[((rr << 4) + cl) << 1];
        int dy = dybase + t, dy2 = dy * dy;
        #pragma unroll
        for (int r = 0; r < 4; r++) {
            float s = acc[t][r] + qa[r] * kv.x + qb[r] * kv.y;
            bool ok = kyok && kxok && (dy2 + dx2c[r] <= 36);
            acc[t][r] = ok ? s : -1e4f;
            mh[r] = fmaxf(mh[r], acc[t][r]);
        }
    }
    #pragma unroll
    for (int s = 1; s < 16; s <<= 1) {
        #pragma unroll
        for (int r = 0; r < 4; r++) mh[r] = fmaxf(mh[r], __shfl_xor(mh[r], s, 64));
    }
    if (cl == 0) {
        float4 t4 = make_float4(mh[0], mh[1], mh[2], mh[3]);
        *(float4*)&mbuf[(kh << 5) + (m << 4) + (kg << 2)] = t4;
    }
    __syncthreads();
    float4 om = *(float4*)&mbuf[((kh ^ 1) << 5) + (m << 4) + (kg << 2)];
    float mf[4];
    mf[0] = fmaxf(mh[0], om.x); mf[1] = fmaxf(mh[1], om.y);
    mf[2] = fmaxf(mh[2], om.z); mf[3] = fmaxf(mh[3], om.w);

    // ---- exp + row sum (cross-wave via sbuf), write P (bf16)
    float sh[4] = {0.f, 0.f, 0.f, 0.f};
    #pragma unroll
    for (int t = 0; t < 10; t++) {
        #pragma unroll
        for (int r = 0; r < 4; r++) {
            float p = __expf(acc[t][r] - mf[r]);
            acc[t][r] = p;
            sh[r] += p;
        }
    }
    #pragma unroll
    for (int s = 1; s < 16; s <<= 1) {
        #pragma unroll
        for (int r = 0; r < 4; r++) sh[r] += __shfl_xor(sh[r], s, 64);
    }
    if (cl == 0) {
        float4 t4 = make_float4(sh[0], sh[1], sh[2], sh[3]);
        *(float4*)&sbuf[(kh << 5) + (m << 4) + (kg << 2)] = t4;
    }
    #pragma unroll
    for (int t = 0; t < 10; t++) {
        int slot = ((kh * 10 + t) << 4) + cl;
        #pragma unroll
        for (int r = 0; r < 4; r++) {
            int q = (m << 4) + (kg << 2) + r;
            Pl[q * 328 + slot] = f2bf(acc[t][r]);
        }
    }
    __syncthreads();
    float4 os = *(float4*)&sbuf[((kh ^ 1) << 5) + (m << 4) + (kg << 2)];
    float rinv[4];
    rinv[0] = 1.f / (sh[0] + os.x); rinv[1] = 1.f / (sh[1] + os.y);
    rinv[2] = 1.f / (sh[2] + os.z); rinv[3] = 1.f / (sh[3] + os.w);

    // ---- PV: this wave's 5 k-tiles (its own P writes), 2 kd n-tiles
    f32x4 oacc0 = {0.f, 0.f, 0.f, 0.f}, oacc1 = {0.f, 0.f, 0.f, 0.f};
    int arow = (m << 4) + cl;
    #pragma unroll
    for (int i2 = 0; i2 < 5; i2++) {
        int kk = kh * 5 + i2;
        bf16x8 ap = *(bf16x8*)&Pl[arow * 328 + (kk << 5) + (kg << 3)];
        bf16x8 bv0 = *(bf16x8*)&vfr[(((kk << 1) << 6) + ll) << 3];
        bf16x8 bv1 = *(bf16x8*)&vfr[((((kk << 1) + 1) << 6) + ll) << 3];
        oacc0 = __builtin_amdgcn_mfma_f32_16x16x32_bf16(ap, bv0, oacc0, 0, 0, 0);
        oacc1 = __builtin_amdgcn_mfma_f32_16x16x32_bf16(ap, bv1, oacc1, 0, 0, 0);
    }
    // normalized partial-O accumulation across kh halves
    #pragma unroll
    for (int r = 0; r < 4; r++) {
        int q = (m << 4) + (kg << 2) + r;
        atomicAdd(&olds[q * 36 + cl],      oacc0[r] * rinv[r]);
        atomicAdd(&olds[q * 36 + cl + 16], oacc1[r] * rinv[r]);
    }
    __syncthreads();

    // ---- epilogue: Y = O * Wout^T via MFMA, scattered f32 stores
    int qe = (m << 4) + cl;
    float4 o1 = *(float4*)&olds[qe * 36 + (kg << 3)];
    float4 o2 = *(float4*)&olds[qe * 36 + (kg << 3) + 4];
    bf16x8 aO;
    aO[0] = (short)f2bf(o1.x); aO[1] = (short)f2bf(o1.y);
    aO[2] = (short)f2bf(o1.z); aO[3] = (short)f2bf(o1.w);
    aO[4] = (short)f2bf(o2.x); aO[5] = (short)f2bf(o2.y);
    aO[6] = (short)f2bf(o2.z); aO[7] = (short)f2bf(o2.w);

    int nqb = (qy0 + qrl) * 32 + qx0;
    #pragma unroll
    for (int e = 0; e < 2; e++) {
        int nt2 = (kh << 1) + e;
        bf16x8 bw = *(bf16x8*)&wfr[((nt2 << 6) + ll) << 3];
        f32x4 z = {0.f, 0.f, 0.f, 0.f};
        f32x4 y = __builtin_amdgcn_mfma_f32_16x16x32_bf16(aO, bw, z, 0, 0, 0);
        int cc = cl + (nt2 << 4);
        #pragma unroll
        for (int r = 0; r < 4; r++)
            out[(((b << 6) + cc) << 10) + nqb + r] = y[r];
    }
}

extern "C" void kernel_launch(void* const* d_in, const int* in_sizes, int n_in,
                              void* d_out, int out_size, void* d_ws, size_t ws_size,
                              hipStream_t stream) {
    const float* x    = (const float*)d_in[0];
    const float* Wq   = (const float*)d_in[1];
    const float* Wk   = (const float*)d_in[2];
    const float* Wv   = (const float*)d_in[3];
    const float* Wqxy = (const float*)d_in[4];
    const float* Wkxy = (const float*)d_in[5];
    const float* Wout = (const float*)d_in[6];
    float* out = (float*)d_out;
    char* wsb  = (char*)d_ws;

    proj_kernel<<<256, 256, 0, stream>>>(x, Wq, Wk, Wv, Wqxy, Wkxy, wsb);
    attn_kernel<<<512, 256, 0, stream>>>(wsb, Wout, out);
}